// Round 4
// baseline (346.770 us; speedup 1.0000x reference)
//
#include <hip/hip_runtime.h>
#include <hip/hip_bf16.h>

typedef unsigned int u32;
typedef unsigned short u16;
using f32x4  = __attribute__((ext_vector_type(4))) float;
using f32x16 = __attribute__((ext_vector_type(16))) float;
using u32x4  = __attribute__((ext_vector_type(4))) u32;
using s16x8  = __attribute__((ext_vector_type(8))) short;

#define DEV static __device__ __forceinline__

DEV u32 pk2(float a, float b) {
  u16 lo = __builtin_bit_cast(u16, __float2bfloat16(a));
  u16 hi = __builtin_bit_cast(u16, __float2bfloat16(b));
  return (u32)lo | ((u32)hi << 16);
}

DEV f32x16 MFMA32(u32x4 a, u32x4 b, f32x16 c) {
  return __builtin_amdgcn_mfma_f32_32x32x16_bf16(
      __builtin_bit_cast(s16x8, a), __builtin_bit_cast(s16x8, b), c, 0, 0, 0);
}

// swaps upper 32 lanes of a with lower 32 lanes of b
DEV void pl32swap(u32& a, u32& b) {
  asm volatile("v_permlane32_swap_b32 %0, %1" : "+v"(a), "+v"(b));
}

// ---------------- pre-kernel 1: per-expert alpha = mean(|W|) ----------------
__global__ void qalpha(const float* __restrict__ w1, const float* __restrict__ w2,
                       float* __restrict__ alphas) {
  int b = blockIdx.x;  // 0..7 -> w1 experts, 8..15 -> w2 experts
  const float* src = (b < 8 ? w1 : w2) + (size_t)(b & 7) * 32768;
  int tid = threadIdx.x;
  float s = 0.f;
  for (int i = tid; i < 32768; i += 256) s += fabsf(src[i]);
  #pragma unroll
  for (int off = 32; off >= 1; off >>= 1) s += __shfl_down(s, off, 64);
  __shared__ float ws4[4];
  if ((tid & 63) == 0) ws4[tid >> 6] = s;
  __syncthreads();
  if (tid == 0) alphas[b] = (ws4[0] + ws4[1] + ws4[2] + ws4[3]) * (1.f / 32768.f);
}

DEV u16 tq1(float v, float thr) {
  return (fabsf(v) > thr) ? (v > 0.f ? (u16)0x3F80 : (u16)0xBF80) : (u16)0;
}
DEV u32 tq2(float a, float b, float thr) {
  return (u32)tq1(a, thr) | ((u32)tq1(b, thr) << 16);
}

// ------- pre-kernel 2: fragment-planar bf16 weight image (coalesced loads) -------
// chunk n = e*8+ht occupies img[n*16384 .. +16384):
//   w1 plane: img[n*16384 + ks*1024 + l*16]  (ks=0..7, l=0..63)
//     = w1q[e][h = ht*32 + (l&31)][k = ks*16 + (l>>5)*8 + 0..7]  (8 bf16)
//   w2 plane: img[n*16384 + 8192 + (ks2*4+ot)*1024 + l*16]
//     = w2q[e][o = ot*32 + (l&31)][k = ht*32 + ks2*16 + (l>>5)*8 + 0..7]
__global__ void qimg(const float* __restrict__ w1, const float* __restrict__ w2,
                     const float* __restrict__ alphas, char* __restrict__ img) {
  int gid = blockIdx.x * 256 + threadIdx.x;  // 65536 total
  int l = gid & 63;
  int col = l & 31, hi = l >> 5;
  const float* src;
  float thr;
  char* dst;
  if (gid < 32768) {
    int ks = (gid >> 6) & 7;
    int n  = gid >> 9;            // e*8+ht
    int e  = n >> 3, ht = n & 7;
    int h  = ht * 32 + col;
    int k0 = ks * 16 + hi * 8;
    src = w1 + (size_t)e * 32768 + h * 128 + k0;
    thr = 0.5f * alphas[e];
    dst = img + (size_t)n * 16384 + ks * 1024 + l * 16;
  } else {
    int id = gid - 32768;
    int sl = (id >> 6) & 7;       // ks2*4 + ot
    int n  = id >> 9;             // e*8 + c
    int e  = n >> 3, c = n & 7;
    int ks2 = sl >> 2, ot = sl & 3;
    int o  = ot * 32 + col;
    int k0 = c * 32 + ks2 * 16 + hi * 8;
    src = w2 + (size_t)e * 32768 + o * 256 + k0;
    thr = 0.5f * alphas[8 + e];
    dst = img + (size_t)n * 16384 + 8192 + sl * 1024 + l * 16;
  }
  float4 v0 = *(const float4*)src;
  float4 v1 = *(const float4*)(src + 4);
  u32 q0 = tq2(v0.x, v0.y, thr), q1 = tq2(v0.z, v0.w, thr);
  u32 q2 = tq2(v1.x, v1.y, thr), q3 = tq2(v1.z, v1.w, thr);
  *(uint4*)dst = make_uint4(q0, q1, q2, q3);
}

// ---------------- main fused kernel ----------------
__global__ __launch_bounds__(256, 2) void moe_main(
    const float* __restrict__ x, const float* __restrict__ b1g,
    const float* __restrict__ b2g, const float* __restrict__ wg,
    const float* __restrict__ bg, const char* __restrict__ img,
    float* __restrict__ out) {
  __shared__ float s_b1[2048];    // [8 e][256 h]
  __shared__ float s_g[8 * 256];  // [8 e][256 t]
  const int tid = threadIdx.x;
  const int w = tid >> 6, l = tid & 63;
  const int col = l & 31, hi = l >> 5;
  const int tokw = blockIdx.x * 256 + w * 64;  // wave's token base

  // ---- b1 -> LDS (one-time copy; covered by the gate barrier)
  {
    const float4* s = (const float4*)b1g;
    float4* d = (float4*)s_b1;
    d[tid] = s[tid];
    d[tid + 256] = s[tid + 256];
  }

  // ---- xf: x fragments (B operand of GEMM1), bf16, kept in regs all kernel
  u32x4 xf[2][8];
  #pragma unroll
  for (int tt = 0; tt < 2; ++tt) {
    #pragma unroll
    for (int ks = 0; ks < 8; ++ks) {
      const float* xp = x + (size_t)(tokw + tt * 32 + col) * 128 + ks * 16 + hi * 8;
      float4 v0 = *(const float4*)xp;
      float4 v1 = *(const float4*)(xp + 4);
      xf[tt][ks] = (u32x4){pk2(v0.x, v0.y), pk2(v0.z, v0.w),
                           pk2(v1.x, v1.y), pk2(v1.z, v1.w)};
    }
  }

  // ---- gate: exact f32 logits -> softmax/T -> top-5 -> renorm -> s_g[8][256]
  {
    int t = blockIdx.x * 256 + tid;
    const float4* xr = (const float4*)(x + (size_t)t * 128);
    const float4* wr = (const float4*)wg;
    float lg[8];
    #pragma unroll
    for (int e = 0; e < 8; ++e) lg[e] = bg[e];
    for (int i = 0; i < 32; ++i) {
      float4 xv = xr[i];
      #pragma unroll
      for (int e = 0; e < 8; ++e) {
        float4 wv = wr[e * 32 + i];
        lg[e] += xv.x * wv.x + xv.y * wv.y + xv.z * wv.z + xv.w * wv.w;
      }
    }
    const float invT = 0.36787944117144233f;  // 1/e
    #pragma unroll
    for (int e = 0; e < 8; ++e) lg[e] *= invT;
    float mx = lg[0];
    #pragma unroll
    for (int e = 1; e < 8; ++e) mx = fmaxf(mx, lg[e]);
    float p[8], den = 0.f;
    #pragma unroll
    for (int e = 0; e < 8; ++e) { p[e] = __expf(lg[e] - mx); den += p[e]; }
    float inv = 1.f / den;
    #pragma unroll
    for (int e = 0; e < 8; ++e) p[e] *= inv;
    float gsel[8], wsum = 0.f;
    #pragma unroll
    for (int e = 0; e < 8; ++e) {
      int rank = 0;
      #pragma unroll
      for (int e2 = 0; e2 < 8; ++e2)
        rank += (p[e2] > p[e]) || (p[e2] == p[e] && e2 < e);
      gsel[e] = (rank < 5) ? p[e] : 0.f;
      wsum += gsel[e];
    }
    float r = 1.f / (wsum + 1e-8f);
    #pragma unroll
    for (int e = 0; e < 8; ++e) s_g[e * 256 + tid] = gsel[e] * r;
  }
  __syncthreads();  // gate + b1 visible; ONLY barrier in the kernel

  // ---- init acc2[ot][tt] = sum_e g[t][e]*b2[e][o] via one K=16 MFMA pass
  f32x16 acc2[4][2];
  {
    u32x4 gf[2];
    #pragma unroll
    for (int tt = 0; tt < 2; ++tt) {
      u32x4 v = (u32x4){0u, 0u, 0u, 0u};
      if (hi == 0) {
        int t = w * 64 + tt * 32 + col;
        v = (u32x4){pk2(s_g[0 * 256 + t], s_g[1 * 256 + t]),
                    pk2(s_g[2 * 256 + t], s_g[3 * 256 + t]),
                    pk2(s_g[4 * 256 + t], s_g[5 * 256 + t]),
                    pk2(s_g[6 * 256 + t], s_g[7 * 256 + t])};
      }
      gf[tt] = v;
    }
    #pragma unroll
    for (int ot = 0; ot < 4; ++ot) {
      u32x4 af = (u32x4){0u, 0u, 0u, 0u};
      if (hi == 0) {
        int o = ot * 32 + col;
        af = (u32x4){pk2(b2g[0 * 128 + o], b2g[1 * 128 + o]),
                     pk2(b2g[2 * 128 + o], b2g[3 * 128 + o]),
                     pk2(b2g[4 * 128 + o], b2g[5 * 128 + o]),
                     pk2(b2g[6 * 128 + o], b2g[7 * 128 + o])};
      }
      f32x16 z{};
      #pragma unroll
      for (int tt = 0; tt < 2; ++tt) acc2[ot][tt] = MFMA32(af, gf[tt], z);
    }
  }

  // ---- chunk loop: 64 chunks, NO barriers, weights global->VGPR (L1/L2-hot)
  const u32 loff = (u32)(l * 16);  // loop-invariant per-lane offset
  const char* wp = img;            // advances 16384/chunk (uniform)

  #pragma unroll 1
  for (int e = 0; e < 8; ++e) {
    const float g0 = s_g[e * 256 + w * 64 + col];
    const float g1 = s_g[e * 256 + w * 64 + 32 + col];
    const float* b1e = s_b1 + e * 256 + hi * 4;

    #pragma unroll 1
    for (int ht = 0; ht < 8; ++ht) {
      // issue all 16 fragment loads up front (G2's fly under G1 compute)
      u32x4 f1[8], f2[8];
      #pragma unroll
      for (int ks = 0; ks < 8; ++ks)
        f1[ks] = *(const u32x4*)(wp + ks * 1024 + loff);
      #pragma unroll
      for (int sl = 0; sl < 8; ++sl)
        f2[sl] = *(const u32x4*)(wp + 8192 + sl * 1024 + loff);

      // --- GEMM1: D1[32h x 64t] for h in [32*ht, 32*ht+32)
      f32x16 a1_0{}, a1_1{};
      __builtin_amdgcn_s_setprio(1);
      #pragma unroll
      for (int ks = 0; ks < 8; ++ks) {
        a1_0 = MFMA32(f1[ks], xf[0][ks], a1_0);
        a1_1 = MFMA32(f1[ks], xf[1][ks], a1_1);
      }
      __builtin_amdgcn_s_setprio(0);

      // --- epilogue: +b1, relu, *gate, pack bf16, permlane -> GEMM2 B-frags
      u32x4 hf[2][2];
      const float* b1b = b1e + ht * 32;
      #pragma unroll
      for (int tt = 0; tt < 2; ++tt) {
        const f32x16& a1 = tt ? a1_1 : a1_0;
        const float g = tt ? g1 : g0;
        u32 u[8];
        #pragma unroll
        for (int rg = 0; rg < 4; ++rg) {
          f32x4 bb = *(const f32x4*)(b1b + rg * 8);
          float h0 = fmaxf(a1[rg * 4 + 0] + bb.x, 0.f) * g;
          float h1 = fmaxf(a1[rg * 4 + 1] + bb.y, 0.f) * g;
          float h2 = fmaxf(a1[rg * 4 + 2] + bb.z, 0.f) * g;
          float h3 = fmaxf(a1[rg * 4 + 3] + bb.w, 0.f) * g;
          u[rg * 2 + 0] = pk2(h0, h1);
          u[rg * 2 + 1] = pk2(h2, h3);
        }
        pl32swap(u[0], u[2]);
        pl32swap(u[1], u[3]);
        pl32swap(u[4], u[6]);
        pl32swap(u[5], u[7]);
        hf[0][tt] = (u32x4){u[0], u[1], u[2], u[3]};
        hf[1][tt] = (u32x4){u[4], u[5], u[6], u[7]};
      }

      // --- GEMM2: acc2[o][t] += w2q[o][k-slice] * hid[k-slice][t]
      __builtin_amdgcn_s_setprio(1);
      #pragma unroll
      for (int ks2 = 0; ks2 < 2; ++ks2) {
        #pragma unroll
        for (int ot = 0; ot < 4; ++ot) {
          u32x4 af = f2[ks2 * 4 + ot];
          acc2[ot][0] = MFMA32(af, hf[ks2][0], acc2[ot][0]);
          acc2[ot][1] = MFMA32(af, hf[ks2][1], acc2[ot][1]);
        }
      }
      __builtin_amdgcn_s_setprio(0);

      wp += 16384;
    }
  }

  // ---- store D2[o][t] -> out[t][o]
  #pragma unroll
  for (int ot = 0; ot < 4; ++ot) {
    #pragma unroll
    for (int tt = 0; tt < 2; ++tt) {
      const f32x16& a = acc2[ot][tt];
      float* op = out + (size_t)(tokw + tt * 32 + col) * 128 + ot * 32 + hi * 4;
      #pragma unroll
      for (int rg = 0; rg < 4; ++rg)
        *(f32x4*)(op + rg * 8) =
            (f32x4){a[rg * 4 + 0], a[rg * 4 + 1], a[rg * 4 + 2], a[rg * 4 + 3]};
    }
  }
}

extern "C" void kernel_launch(void* const* d_in, const int* in_sizes, int n_in,
                              void* d_out, int out_size, void* d_ws, size_t ws_size,
                              hipStream_t stream) {
  const float* x  = (const float*)d_in[0];
  const float* w1 = (const float*)d_in[1];
  const float* b1 = (const float*)d_in[2];
  const float* w2 = (const float*)d_in[3];
  const float* b2 = (const float*)d_in[4];
  const float* wg = (const float*)d_in[5];
  const float* bg = (const float*)d_in[6];
  float* out = (float*)d_out;

  if (ws_size < 1048704) return;
  char* ws = (char*)d_ws;
  char* img = ws;                          // 1 MB fragment-planar image
  float* alphas = (float*)(ws + 1048576);  // 16 f32

  int ntok = in_sizes[0] / 128;
  int nblk = ntok / 256;

  qalpha<<<16, 256, 0, stream>>>(w1, w2, alphas);
  qimg<<<256, 256, 0, stream>>>(w1, w2, alphas, img);
  moe_main<<<nblk, 256, 0, stream>>>(x, b1, b2, wg, bg, img, out);
}

// Round 5
// 215.163 us; speedup vs baseline: 1.6117x; 1.6117x over previous
//
#include <hip/hip_runtime.h>
#include <hip/hip_bf16.h>

typedef unsigned int u32;
typedef unsigned short u16;
using f32x4  = __attribute__((ext_vector_type(4))) float;
using f32x16 = __attribute__((ext_vector_type(16))) float;
using u32x4  = __attribute__((ext_vector_type(4))) u32;
using s16x8  = __attribute__((ext_vector_type(8))) short;

#define DEV static __device__ __forceinline__

DEV u32 pk2(float a, float b) {
  u16 lo = __builtin_bit_cast(u16, __float2bfloat16(a));
  u16 hi = __builtin_bit_cast(u16, __float2bfloat16(b));
  return (u32)lo | ((u32)hi << 16);
}

DEV f32x16 MFMA32(u32x4 a, u32x4 b, f32x16 c) {
  return __builtin_amdgcn_mfma_f32_32x32x16_bf16(
      __builtin_bit_cast(s16x8, a), __builtin_bit_cast(s16x8, b), c, 0, 0, 0);
}

// swaps upper 32 lanes of a with lower 32 lanes of b
DEV void pl32swap(u32& a, u32& b) {
  asm volatile("v_permlane32_swap_b32 %0, %1" : "+v"(a), "+v"(b));
}

// ---------------- pre-kernel 1: per-expert alpha = mean(|W|) ----------------
__global__ void qalpha(const float* __restrict__ w1, const float* __restrict__ w2,
                       float* __restrict__ alphas) {
  int b = blockIdx.x;  // 0..7 -> w1 experts, 8..15 -> w2 experts
  const float* src = (b < 8 ? w1 : w2) + (size_t)(b & 7) * 32768;
  int tid = threadIdx.x;
  float s = 0.f;
  for (int i = tid; i < 32768; i += 256) s += fabsf(src[i]);
  #pragma unroll
  for (int off = 32; off >= 1; off >>= 1) s += __shfl_down(s, off, 64);
  __shared__ float ws4[4];
  if ((tid & 63) == 0) ws4[tid >> 6] = s;
  __syncthreads();
  if (tid == 0) alphas[b] = (ws4[0] + ws4[1] + ws4[2] + ws4[3]) * (1.f / 32768.f);
}

DEV u16 tq1(float v, float thr) {
  return (fabsf(v) > thr) ? (v > 0.f ? (u16)0x3F80 : (u16)0xBF80) : (u16)0;
}
DEV u32 tq2(float a, float b, float thr) {
  return (u32)tq1(a, thr) | ((u32)tq1(b, thr) << 16);
}

// ------- pre-kernel 2: fragment-planar bf16 weight image (coalesced loads) -------
// chunk n = e*8+ht occupies img[n*16384 .. +16384):
//   w1 plane: img[n*16384 + ks*1024 + l*16]  (ks=0..7, l=0..63)
//     = w1q[e][h = ht*32 + (l&31)][k = ks*16 + (l>>5)*8 + 0..7]  (8 bf16)
//   w2 plane: img[n*16384 + 8192 + (ks2*4+ot)*1024 + l*16]
//     = w2q[e][o = ot*32 + (l&31)][k = ht*32 + ks2*16 + (l>>5)*8 + 0..7]
__global__ void qimg(const float* __restrict__ w1, const float* __restrict__ w2,
                     const float* __restrict__ alphas, char* __restrict__ img) {
  int gid = blockIdx.x * 256 + threadIdx.x;  // 65536 total
  int l = gid & 63;
  int col = l & 31, hi = l >> 5;
  const float* src;
  float thr;
  char* dst;
  if (gid < 32768) {
    int ks = (gid >> 6) & 7;
    int n  = gid >> 9;            // e*8+ht
    int e  = n >> 3, ht = n & 7;
    int h  = ht * 32 + col;
    int k0 = ks * 16 + hi * 8;
    src = w1 + (size_t)e * 32768 + h * 128 + k0;
    thr = 0.5f * alphas[e];
    dst = img + (size_t)n * 16384 + ks * 1024 + l * 16;
  } else {
    int id = gid - 32768;
    int sl = (id >> 6) & 7;       // ks2*4 + ot
    int n  = id >> 9;             // e*8 + c
    int e  = n >> 3, c = n & 7;
    int ks2 = sl >> 2, ot = sl & 3;
    int o  = ot * 32 + col;
    int k0 = c * 32 + ks2 * 16 + hi * 8;
    src = w2 + (size_t)e * 32768 + o * 256 + k0;
    thr = 0.5f * alphas[8 + e];
    dst = img + (size_t)n * 16384 + 8192 + sl * 1024 + l * 16;
  }
  float4 v0 = *(const float4*)src;
  float4 v1 = *(const float4*)(src + 4);
  u32 q0 = tq2(v0.x, v0.y, thr), q1 = tq2(v0.z, v0.w, thr);
  u32 q2 = tq2(v1.x, v1.y, thr), q3 = tq2(v1.z, v1.w, thr);
  *(uint4*)dst = make_uint4(q0, q1, q2, q3);
}

// ---------------- main fused kernel ----------------
// 512 threads = 8 waves x 32 tokens. No barriers in the chunk loop; weights
// stream global->VGPR (L1/L2-hot, 1MB image shared chip-wide). acc2 = 64 regs.
__global__ __launch_bounds__(512, 2) void moe_main(
    const float* __restrict__ x, const float* __restrict__ b1g,
    const float* __restrict__ b2g, const float* __restrict__ wg,
    const float* __restrict__ bg, const char* __restrict__ img,
    float* __restrict__ out) {
  __shared__ float s_b1[2048];    // [8 e][256 h]
  __shared__ float s_g[2048];     // [8 e][256 t]
  const int tid = threadIdx.x;
  const int w = tid >> 6, l = tid & 63;
  const int col = l & 31, hi = l >> 5;
  const int tokw = blockIdx.x * 256 + w * 32;  // wave's token base

  // ---- xf: x fragments (B operand of GEMM1), bf16, kept in regs all kernel
  u32x4 xf[8];
  #pragma unroll
  for (int ks = 0; ks < 8; ++ks) {
    const float* xp = x + (size_t)(tokw + col) * 128 + ks * 16 + hi * 8;
    float4 v0 = *(const float4*)xp;
    float4 v1 = *(const float4*)(xp + 4);
    xf[ks] = (u32x4){pk2(v0.x, v0.y), pk2(v0.z, v0.w),
                     pk2(v1.x, v1.y), pk2(v1.z, v1.w)};
  }

  // ---- gate (tid<256) or b1->LDS copy (tid>=256)
  if (tid < 256) {
    int t = blockIdx.x * 256 + tid;
    const float4* xr = (const float4*)(x + (size_t)t * 128);
    const float4* wr = (const float4*)wg;
    float lg[8];
    #pragma unroll
    for (int e = 0; e < 8; ++e) lg[e] = bg[e];
    for (int i = 0; i < 32; ++i) {
      float4 xv = xr[i];
      #pragma unroll
      for (int e = 0; e < 8; ++e) {
        float4 wv = wr[e * 32 + i];
        lg[e] += xv.x * wv.x + xv.y * wv.y + xv.z * wv.z + xv.w * wv.w;
      }
    }
    const float invT = 0.36787944117144233f;  // 1/e
    #pragma unroll
    for (int e = 0; e < 8; ++e) lg[e] *= invT;
    float mx = lg[0];
    #pragma unroll
    for (int e = 1; e < 8; ++e) mx = fmaxf(mx, lg[e]);
    float p[8], den = 0.f;
    #pragma unroll
    for (int e = 0; e < 8; ++e) { p[e] = __expf(lg[e] - mx); den += p[e]; }
    float inv = 1.f / den;
    #pragma unroll
    for (int e = 0; e < 8; ++e) p[e] *= inv;
    float gsel[8], wsum = 0.f;
    #pragma unroll
    for (int e = 0; e < 8; ++e) {
      int rank = 0;
      #pragma unroll
      for (int e2 = 0; e2 < 8; ++e2)
        rank += (p[e2] > p[e]) || (p[e2] == p[e] && e2 < e);
      gsel[e] = (rank < 5) ? p[e] : 0.f;
      wsum += gsel[e];
    }
    float r = 1.f / (wsum + 1e-8f);
    #pragma unroll
    for (int e = 0; e < 8; ++e) s_g[e * 256 + tid] = gsel[e] * r;
  } else {
    int t2 = tid - 256;
    ((float4*)s_b1)[t2] = ((const float4*)b1g)[t2];
    ((float4*)s_b1)[t2 + 256] = ((const float4*)b1g)[t2 + 256];
  }
  __syncthreads();  // ONLY barrier in the kernel

  // ---- init acc2[ot] = sum_e g[t][e]*b2[e][o] via one K=16 MFMA pass
  f32x16 acc2[4];
  {
    u32x4 gf = (u32x4){0u, 0u, 0u, 0u};
    if (hi == 0) {
      int t = w * 32 + col;
      gf = (u32x4){pk2(s_g[0 * 256 + t], s_g[1 * 256 + t]),
                   pk2(s_g[2 * 256 + t], s_g[3 * 256 + t]),
                   pk2(s_g[4 * 256 + t], s_g[5 * 256 + t]),
                   pk2(s_g[6 * 256 + t], s_g[7 * 256 + t])};
    }
    #pragma unroll
    for (int ot = 0; ot < 4; ++ot) {
      u32x4 af = (u32x4){0u, 0u, 0u, 0u};
      if (hi == 0) {
        int o = ot * 32 + col;
        af = (u32x4){pk2(b2g[0 * 128 + o], b2g[1 * 128 + o]),
                     pk2(b2g[2 * 128 + o], b2g[3 * 128 + o]),
                     pk2(b2g[4 * 128 + o], b2g[5 * 128 + o]),
                     pk2(b2g[6 * 128 + o], b2g[7 * 128 + o])};
      }
      f32x16 z{};
      acc2[ot] = MFMA32(af, gf, z);
    }
  }

  const u32 loff = (u32)(l * 16);

  // one chunk: GEMM1 (8 MFMA) -> epilogue -> GEMM2 (8 MFMA). f2 passed in.
  auto chunk_body = [&](const u32x4 (&cur)[8], const u32x4 (&f2)[8], int n) {
    f32x16 a1{};
    __builtin_amdgcn_s_setprio(1);
    #pragma unroll
    for (int ks = 0; ks < 8; ++ks) a1 = MFMA32(cur[ks], xf[ks], a1);
    __builtin_amdgcn_s_setprio(0);

    const int e = n >> 3, ht = n & 7;
    const float g = s_g[e * 256 + w * 32 + col];
    const float* b1b = s_b1 + e * 256 + ht * 32 + hi * 4;
    u32 u[8];
    #pragma unroll
    for (int rg = 0; rg < 4; ++rg) {
      f32x4 bb = *(const f32x4*)(b1b + rg * 8);
      float h0 = fmaxf(a1[rg * 4 + 0] + bb.x, 0.f) * g;
      float h1 = fmaxf(a1[rg * 4 + 1] + bb.y, 0.f) * g;
      float h2 = fmaxf(a1[rg * 4 + 2] + bb.z, 0.f) * g;
      float h3 = fmaxf(a1[rg * 4 + 3] + bb.w, 0.f) * g;
      u[rg * 2 + 0] = pk2(h0, h1);
      u[rg * 2 + 1] = pk2(h2, h3);
    }
    pl32swap(u[0], u[2]);
    pl32swap(u[1], u[3]);
    pl32swap(u[4], u[6]);
    pl32swap(u[5], u[7]);
    u32x4 hf0 = (u32x4){u[0], u[1], u[2], u[3]};
    u32x4 hf1 = (u32x4){u[4], u[5], u[6], u[7]};

    __builtin_amdgcn_s_setprio(1);
    #pragma unroll
    for (int ot = 0; ot < 4; ++ot) acc2[ot] = MFMA32(f2[ot], hf0, acc2[ot]);
    #pragma unroll
    for (int ot = 0; ot < 4; ++ot) acc2[ot] = MFMA32(f2[4 + ot], hf1, acc2[ot]);
    __builtin_amdgcn_s_setprio(0);
  };

  // ---- chunk loop: 64 chunks, no barriers; f1 double-buffered (static regs)
  u32x4 f1a[8], f1b[8];
  #pragma unroll
  for (int ks = 0; ks < 8; ++ks)
    f1a[ks] = *(const u32x4*)(img + ks * 1024 + loff);

  #pragma unroll 1
  for (int n2 = 0; n2 < 32; ++n2) {
    {  // even chunk n = 2*n2: compute from f1a, prefetch f1b (always valid)
      const int n = 2 * n2;
      const char* wp = img + (size_t)n * 16384;
      u32x4 f2[8];
      #pragma unroll
      for (int sl = 0; sl < 8; ++sl)
        f2[sl] = *(const u32x4*)(wp + 8192 + sl * 1024 + loff);
      #pragma unroll
      for (int ks = 0; ks < 8; ++ks)
        f1b[ks] = *(const u32x4*)(wp + 16384 + ks * 1024 + loff);
      chunk_body(f1a, f2, n);
    }
    {  // odd chunk n = 2*n2+1: compute from f1b, prefetch f1a
      const int n = 2 * n2 + 1;
      const char* wp = img + (size_t)n * 16384;
      u32x4 f2[8];
      #pragma unroll
      for (int sl = 0; sl < 8; ++sl)
        f2[sl] = *(const u32x4*)(wp + 8192 + sl * 1024 + loff);
      if (n < 63) {
        #pragma unroll
        for (int ks = 0; ks < 8; ++ks)
          f1a[ks] = *(const u32x4*)(wp + 16384 + ks * 1024 + loff);
      }
      chunk_body(f1b, f2, n);
    }
  }

  // ---- store D2[o][t] -> out[t][o]
  #pragma unroll
  for (int ot = 0; ot < 4; ++ot) {
    const f32x16& a = acc2[ot];
    float* op = out + (size_t)(tokw + col) * 128 + ot * 32 + hi * 4;
    #pragma unroll
    for (int rg = 0; rg < 4; ++rg)
      *(f32x4*)(op + rg * 8) =
          (f32x4){a[rg * 4 + 0], a[rg * 4 + 1], a[rg * 4 + 2], a[rg * 4 + 3]};
  }
}

extern "C" void kernel_launch(void* const* d_in, const int* in_sizes, int n_in,
                              void* d_out, int out_size, void* d_ws, size_t ws_size,
                              hipStream_t stream) {
  const float* x  = (const float*)d_in[0];
  const float* w1 = (const float*)d_in[1];
  const float* b1 = (const float*)d_in[2];
  const float* w2 = (const float*)d_in[3];
  const float* b2 = (const float*)d_in[4];
  const float* wg = (const float*)d_in[5];
  const float* bg = (const float*)d_in[6];
  float* out = (float*)d_out;

  if (ws_size < 1048704) return;
  char* ws = (char*)d_ws;
  char* img = ws;                          // 1 MB fragment-planar image
  float* alphas = (float*)(ws + 1048576);  // 16 f32

  int ntok = in_sizes[0] / 128;
  int nblk = ntok / 256;

  qalpha<<<16, 256, 0, stream>>>(w1, w2, alphas);
  qimg<<<256, 256, 0, stream>>>(w1, w2, alphas, img);
  moe_main<<<nblk, 512, 0, stream>>>(x, b1, b2, wg, bg, img, out);
}

// Round 6
// 196.855 us; speedup vs baseline: 1.7616x; 1.0930x over previous
//
#include <hip/hip_runtime.h>
#include <hip/hip_bf16.h>

typedef unsigned int u32;
typedef unsigned short u16;
using f32x4  = __attribute__((ext_vector_type(4))) float;
using f32x16 = __attribute__((ext_vector_type(16))) float;
using u32x4  = __attribute__((ext_vector_type(4))) u32;
using s16x8  = __attribute__((ext_vector_type(8))) short;

#define DEV static __device__ __forceinline__

DEV u32 pk2(float a, float b) {
  u16 lo = __builtin_bit_cast(u16, __float2bfloat16(a));
  u16 hi = __builtin_bit_cast(u16, __float2bfloat16(b));
  return (u32)lo | ((u32)hi << 16);
}

DEV f32x16 MFMA32(u32x4 a, u32x4 b, f32x16 c) {
  return __builtin_amdgcn_mfma_f32_32x32x16_bf16(
      __builtin_bit_cast(s16x8, a), __builtin_bit_cast(s16x8, b), c, 0, 0, 0);
}

// swaps upper 32 lanes of a with lower 32 lanes of b
DEV void pl32swap(u32& a, u32& b) {
  asm volatile("v_permlane32_swap_b32 %0, %1" : "+v"(a), "+v"(b));
}

typedef const __attribute__((address_space(1))) u32 gu32;
typedef __attribute__((address_space(3))) u32 lu32;

DEV void load_lds16(const void* g, void* l) {
  __builtin_amdgcn_global_load_lds((gu32*)g, (lu32*)l, 16, 0, 0);
}

// ---------------- pre-kernel 1: per-expert alpha = mean(|W|) ----------------
__global__ void qalpha(const float* __restrict__ w1, const float* __restrict__ w2,
                       float* __restrict__ alphas) {
  int b = blockIdx.x;  // 0..7 -> w1 experts, 8..15 -> w2 experts
  const float* src = (b < 8 ? w1 : w2) + (size_t)(b & 7) * 32768;
  int tid = threadIdx.x;
  float s = 0.f;
  for (int i = tid; i < 32768; i += 256) s += fabsf(src[i]);
  #pragma unroll
  for (int off = 32; off >= 1; off >>= 1) s += __shfl_down(s, off, 64);
  __shared__ float ws4[4];
  if ((tid & 63) == 0) ws4[tid >> 6] = s;
  __syncthreads();
  if (tid == 0) alphas[b] = (ws4[0] + ws4[1] + ws4[2] + ws4[3]) * (1.f / 32768.f);
}

DEV u16 tq1(float v, float thr) {
  return (fabsf(v) > thr) ? (v > 0.f ? (u16)0x3F80 : (u16)0xBF80) : (u16)0;
}
DEV u32 tq2(float a, float b, float thr) {
  return (u32)tq1(a, thr) | ((u32)tq1(b, thr) << 16);
}

// ------- pre-kernel 2: fragment-planar bf16 weight image (coalesced loads) -------
// chunk n = e*8+ht occupies img[n*16384 .. +16384):
//   w1 plane: img[n*16384 + ks*1024 + l*16]  (ks=0..7, l=0..63)
//     = w1q[e][h = ht*32 + (l&31)][k = ks*16 + (l>>5)*8 + 0..7]  (8 bf16)
//   w2 plane: img[n*16384 + 8192 + (ks2*4+ot)*1024 + l*16]
//     = w2q[e][o = ot*32 + (l&31)][k = ht*32 + ks2*16 + (l>>5)*8 + 0..7]
__global__ void qimg(const float* __restrict__ w1, const float* __restrict__ w2,
                     const float* __restrict__ alphas, char* __restrict__ img) {
  int gid = blockIdx.x * 256 + threadIdx.x;  // 65536 total
  int l = gid & 63;
  int col = l & 31, hi = l >> 5;
  const float* src;
  float thr;
  char* dst;
  if (gid < 32768) {
    int ks = (gid >> 6) & 7;
    int n  = gid >> 9;            // e*8+ht
    int e  = n >> 3, ht = n & 7;
    int h  = ht * 32 + col;
    int k0 = ks * 16 + hi * 8;
    src = w1 + (size_t)e * 32768 + h * 128 + k0;
    thr = 0.5f * alphas[e];
    dst = img + (size_t)n * 16384 + ks * 1024 + l * 16;
  } else {
    int id = gid - 32768;
    int sl = (id >> 6) & 7;       // ks2*4 + ot
    int n  = id >> 9;             // e*8 + c
    int e  = n >> 3, c = n & 7;
    int ks2 = sl >> 2, ot = sl & 3;
    int o  = ot * 32 + col;
    int k0 = c * 32 + ks2 * 16 + hi * 8;
    src = w2 + (size_t)e * 32768 + o * 256 + k0;
    thr = 0.5f * alphas[8 + e];
    dst = img + (size_t)n * 16384 + 8192 + sl * 1024 + l * 16;
  }
  float4 v0 = *(const float4*)src;
  float4 v1 = *(const float4*)(src + 4);
  u32 q0 = tq2(v0.x, v0.y, thr), q1 = tq2(v0.z, v0.w, thr);
  u32 q2 = tq2(v1.x, v1.y, thr), q3 = tq2(v1.z, v1.w, thr);
  *(uint4*)dst = make_uint4(q0, q1, q2, q3);
}

// ---------------- main fused kernel ----------------
// 256 thr = 4 waves x 32 tokens; 2 blocks/CU (independent barriers -> anti-phase).
// LDS: w1 ring-3 (24K) | w2 ring-4 (32K) | b1 (8K) | gate (4K) = 68K.
// Pipeline: iter n = [vmcnt(4); s_barrier; ds_read w1(n)+G1(n)->a1_cur;
//                    stage(n+2); epilogue+G2(n-1) from a1_prev (fully drained)].
#define R1_OFF 0
#define R2_OFF 24576
#define B1_OFF 57344
#define G_OFF  65536
#define SMEM_BYTES 69632

__global__ __launch_bounds__(256, 2) void moe_main(
    const float* __restrict__ x, const float* __restrict__ b1g,
    const float* __restrict__ b2g, const float* __restrict__ wg,
    const float* __restrict__ bg, const char* __restrict__ img,
    float* __restrict__ out) {
  extern __shared__ char smem[];
  char* R1 = smem + R1_OFF;
  char* R2 = smem + R2_OFF;
  float* s_b1 = (float*)(smem + B1_OFF);  // [8 e][256 h]
  float* s_g  = (float*)(smem + G_OFF);   // [8 e][128 t]
  const int tid = threadIdx.x;
  const int w = tid >> 6, l = tid & 63;
  const int col = l & 31, hi = l >> 5;
  const int tokw = blockIdx.x * 128 + w * 32;
  const u32 loff = (u32)(l * 16);

  // each wave stages planes {w, w+4} (w1) and {w+8, w+12} (w2) of a chunk
  auto stage = [&](int n) {
    const char* src = img + (size_t)n * 16384 + w * 1024 + loff;
    char* d1 = R1 + (n % 3) * 8192 + w * 1024;
    char* d2 = R2 + (n % 4) * 8192 + w * 1024;
    load_lds16(src,         d1);
    load_lds16(src + 4096,  d1 + 4096);
    load_lds16(src + 8192,  d2);
    load_lds16(src + 12288, d2 + 4096);
  };

  // prologue staging: chunks 0,1 (latency hidden under gate compute)
  stage(0);
  stage(1);

  // ---- xf: x fragments (B operand of GEMM1), bf16, in regs all kernel
  u32x4 xf[8];
  #pragma unroll
  for (int ks = 0; ks < 8; ++ks) {
    const float* xp = x + (size_t)(tokw + col) * 128 + ks * 16 + hi * 8;
    float4 v0 = *(const float4*)xp;
    float4 v1 = *(const float4*)(xp + 4);
    xf[ks] = (u32x4){pk2(v0.x, v0.y), pk2(v0.z, v0.w),
                     pk2(v1.x, v1.y), pk2(v1.z, v1.w)};
  }

  // ---- gate (tid<128) or b1->LDS copy (tid>=128)
  if (tid < 128) {
    int t = blockIdx.x * 128 + tid;
    const float4* xr = (const float4*)(x + (size_t)t * 128);
    const float4* wr = (const float4*)wg;
    float lg[8];
    #pragma unroll
    for (int e = 0; e < 8; ++e) lg[e] = bg[e];
    for (int i = 0; i < 32; ++i) {
      float4 xv = xr[i];
      #pragma unroll
      for (int e = 0; e < 8; ++e) {
        float4 wv = wr[e * 32 + i];
        lg[e] += xv.x * wv.x + xv.y * wv.y + xv.z * wv.z + xv.w * wv.w;
      }
    }
    const float invT = 0.36787944117144233f;  // 1/e
    #pragma unroll
    for (int e = 0; e < 8; ++e) lg[e] *= invT;
    float mx = lg[0];
    #pragma unroll
    for (int e = 1; e < 8; ++e) mx = fmaxf(mx, lg[e]);
    float p[8], den = 0.f;
    #pragma unroll
    for (int e = 0; e < 8; ++e) { p[e] = __expf(lg[e] - mx); den += p[e]; }
    float inv = 1.f / den;
    #pragma unroll
    for (int e = 0; e < 8; ++e) p[e] *= inv;
    float gsel[8], wsum = 0.f;
    #pragma unroll
    for (int e = 0; e < 8; ++e) {
      int rank = 0;
      #pragma unroll
      for (int e2 = 0; e2 < 8; ++e2)
        rank += (p[e2] > p[e]) || (p[e2] == p[e] && e2 < e);
      gsel[e] = (rank < 5) ? p[e] : 0.f;
      wsum += gsel[e];
    }
    float r = 1.f / (wsum + 1e-8f);
    #pragma unroll
    for (int e = 0; e < 8; ++e) s_g[e * 128 + tid] = gsel[e] * r;
  } else {
    int t2 = tid - 128;  // 0..127 -> copy 2048 floats = 512 float4
    #pragma unroll
    for (int k = 0; k < 4; ++k)
      ((float4*)s_b1)[t2 + k * 128] = ((const float4*)b1g)[t2 + k * 128];
  }
  __syncthreads();  // gate+b1 visible; drains prologue staging (vmcnt 0)

  // ---- init acc2[ot] = sum_e g[t][e]*b2[e][o] via one K=16 MFMA pass
  f32x16 acc2[4];
  {
    u32x4 gf = (u32x4){0u, 0u, 0u, 0u};
    if (hi == 0) {
      int t = w * 32 + col;
      gf = (u32x4){pk2(s_g[0 * 128 + t], s_g[1 * 128 + t]),
                   pk2(s_g[2 * 128 + t], s_g[3 * 128 + t]),
                   pk2(s_g[4 * 128 + t], s_g[5 * 128 + t]),
                   pk2(s_g[6 * 128 + t], s_g[7 * 128 + t])};
    }
    #pragma unroll
    for (int ot = 0; ot < 4; ++ot) {
      u32x4 af = (u32x4){0u, 0u, 0u, 0u};
      if (hi == 0) {
        int o = ot * 32 + col;
        af = (u32x4){pk2(b2g[0 * 128 + o], b2g[1 * 128 + o]),
                     pk2(b2g[2 * 128 + o], b2g[3 * 128 + o]),
                     pk2(b2g[4 * 128 + o], b2g[5 * 128 + o]),
                     pk2(b2g[6 * 128 + o], b2g[7 * 128 + o])};
      }
      f32x16 z{};
      acc2[ot] = MFMA32(af, gf, z);
    }
  }

  // ---- pipelined chunk loop
  auto G1 = [&](int n, f32x16& a1) {
    const char* w1c = R1 + (n % 3) * 8192;
    a1 = f32x16{};
    __builtin_amdgcn_s_setprio(1);
    #pragma unroll
    for (int ks = 0; ks < 8; ++ks) {
      u32x4 f = *(const u32x4*)(w1c + ks * 1024 + loff);
      a1 = MFMA32(f, xf[ks], a1);
    }
    __builtin_amdgcn_s_setprio(0);
  };

  auto EPI_G2 = [&](int m, const f32x16& a1) {
    const int e = m >> 3, ht = m & 7;
    const float g = s_g[e * 128 + w * 32 + col];
    const float* b1b = s_b1 + e * 256 + ht * 32 + hi * 4;
    u32 u[8];
    #pragma unroll
    for (int rg = 0; rg < 4; ++rg) {
      f32x4 bb = *(const f32x4*)(b1b + rg * 8);
      float h0 = fmaxf(a1[rg * 4 + 0] + bb.x, 0.f) * g;
      float h1 = fmaxf(a1[rg * 4 + 1] + bb.y, 0.f) * g;
      float h2 = fmaxf(a1[rg * 4 + 2] + bb.z, 0.f) * g;
      float h3 = fmaxf(a1[rg * 4 + 3] + bb.w, 0.f) * g;
      u[rg * 2 + 0] = pk2(h0, h1);
      u[rg * 2 + 1] = pk2(h2, h3);
    }
    pl32swap(u[0], u[2]);
    pl32swap(u[1], u[3]);
    pl32swap(u[4], u[6]);
    pl32swap(u[5], u[7]);
    u32x4 hf0 = (u32x4){u[0], u[1], u[2], u[3]};
    u32x4 hf1 = (u32x4){u[4], u[5], u[6], u[7]};
    const char* w2c = R2 + (m % 4) * 8192;
    __builtin_amdgcn_s_setprio(1);
    #pragma unroll
    for (int ot = 0; ot < 4; ++ot)
      acc2[ot] = MFMA32(*(const u32x4*)(w2c + ot * 1024 + loff), hf0, acc2[ot]);
    #pragma unroll
    for (int ot = 0; ot < 4; ++ot)
      acc2[ot] = MFMA32(*(const u32x4*)(w2c + (4 + ot) * 1024 + loff), hf1, acc2[ot]);
    __builtin_amdgcn_s_setprio(0);
  };

#define PIPE_BAR4                                         \
  do {                                                    \
    asm volatile("s_waitcnt vmcnt(4)" ::: "memory");      \
    __builtin_amdgcn_s_barrier();                         \
    __builtin_amdgcn_sched_barrier(0);                    \
  } while (0)

  f32x16 a1A, a1B;

  // iter 0: no epilogue yet
  PIPE_BAR4;
  G1(0, a1A);
  stage(2);

  #pragma unroll 1
  for (int n2 = 0; n2 < 31; ++n2) {
    const int no = 2 * n2 + 1;  // odd chunk
    PIPE_BAR4;
    G1(no, a1B);
    stage(no + 2);              // <= 63
    EPI_G2(no - 1, a1A);
    const int ne = 2 * n2 + 2;  // even chunk
    PIPE_BAR4;
    G1(ne, a1A);
    if (n2 < 30) stage(ne + 2);
    EPI_G2(ne - 1, a1B);
  }

  // iter 63: last G1 (needs chunk 63 fully landed -> vmcnt 0)
  asm volatile("s_waitcnt vmcnt(0)" ::: "memory");
  __builtin_amdgcn_s_barrier();
  __builtin_amdgcn_sched_barrier(0);
  G1(63, a1B);
  EPI_G2(62, a1A);
  // iter 64: final epilogue
  EPI_G2(63, a1B);

  // ---- store D2[o][t] -> out[t][o]
  #pragma unroll
  for (int ot = 0; ot < 4; ++ot) {
    const f32x16& a = acc2[ot];
    float* op = out + (size_t)(tokw + col) * 128 + ot * 32 + hi * 4;
    #pragma unroll
    for (int rg = 0; rg < 4; ++rg)
      *(f32x4*)(op + rg * 8) =
          (f32x4){a[rg * 4 + 0], a[rg * 4 + 1], a[rg * 4 + 2], a[rg * 4 + 3]};
  }
}

extern "C" void kernel_launch(void* const* d_in, const int* in_sizes, int n_in,
                              void* d_out, int out_size, void* d_ws, size_t ws_size,
                              hipStream_t stream) {
  const float* x  = (const float*)d_in[0];
  const float* w1 = (const float*)d_in[1];
  const float* b1 = (const float*)d_in[2];
  const float* w2 = (const float*)d_in[3];
  const float* b2 = (const float*)d_in[4];
  const float* wg = (const float*)d_in[5];
  const float* bg = (const float*)d_in[6];
  float* out = (float*)d_out;

  if (ws_size < 1048704) return;
  char* ws = (char*)d_ws;
  char* img = ws;                          // 1 MB fragment-planar image
  float* alphas = (float*)(ws + 1048576);  // 16 f32

  int ntok = in_sizes[0] / 128;
  int nblk = ntok / 128;

  qalpha<<<16, 256, 0, stream>>>(w1, w2, alphas);
  qimg<<<256, 256, 0, stream>>>(w1, w2, alphas, img);

  hipFuncSetAttribute(reinterpret_cast<const void*>(moe_main),
                      hipFuncAttributeMaxDynamicSharedMemorySize, SMEM_BYTES);
  moe_main<<<nblk, 256, SMEM_BYTES, stream>>>(x, b1, b2, wg, bg, img, out);
}